// Round 3
// baseline (410.662 us; speedup 1.0000x reference)
//
#include <hip/hip_runtime.h>

// Problem constants (B=8, C=512, H=W=64, K=19 classes)
#define NCLS   19
#define NB     8
#define NC     512
#define NHW    4096      // 64*64
#define EPSM   1e-6f     // mean denominator eps
#define EPSC   1e-8f     // cosine eps

// Workspace layout (bytes)
#define OFF_LABELS   0u          // int32 [NB*NHW]
#define OFF_COUNTS   131072u     // float [NB*NCLS]
#define OFF_SUMS_S0  132096u     // float [NB][NCLS][NC] partial half 0 (becomes means)
#define OFF_SUMS_S1  443392u     // float [NB][NCLS][NC] partial half 1
#define OFF_SUMS_T0  754688u
#define OFF_SUMS_T1  1065984u
#define OFF_NORM_S   1377280u
#define OFF_NORM_T   1378304u
#define OFF_PART     1379328u    // float [4 arrays][8 chunks][NB*NHW] = 4 MB
// total ~5.6 MB

// ---------------------------------------------------------------------------
// Wave-64 sum via DPP (VALU pipe only, no LDS). Result valid in lane 63.
template<int CTRL>
__device__ __forceinline__ float dpp_add(float x) {
    int y = __builtin_amdgcn_update_dpp(0, __float_as_int(x), CTRL, 0xf, 0xf, false);
    return x + __int_as_float(y);
}
__device__ __forceinline__ float wave64_sum(float x) {
    x = dpp_add<0x111>(x);   // row_shr:1
    x = dpp_add<0x112>(x);   // row_shr:2
    x = dpp_add<0x114>(x);   // row_shr:4
    x = dpp_add<0x118>(x);   // row_shr:8
    x = dpp_add<0x142>(x);   // row_bcast:15
    x = dpp_add<0x143>(x);   // row_bcast:31 -> lane63 has total
    return x;
}

// ---------------------------------------------------------------------------
// Kernel 1: nearest-resize labels (512x512 -> 64x64) + per-batch class counts
__global__ __launch_bounds__(256) void k_labels(const int* __restrict__ target,
                                                int* __restrict__ labels,
                                                float* __restrict__ counts) {
    __shared__ int hist[NCLS];
    const int b = blockIdx.x;
    const int t = threadIdx.x;
    if (t < NCLS) hist[t] = 0;
    __syncthreads();
    const int* tb = target + (size_t)b * 512 * 512;
    #pragma unroll
    for (int i = 0; i < 16; ++i) {
        int n = t + i * 256;
        int y = n >> 6, x = n & 63;
        int l = tb[(y * 8) * 512 + x * 8];
        labels[b * NHW + n] = l;
        if (l >= 0 && l < NCLS) atomicAdd(&hist[l], 1);
    }
    __syncthreads();
    if (t < NCLS) counts[b * NCLS + t] = (float)hist[t];
}

// ---------------------------------------------------------------------------
// Kernel 2: per-class channel sums, register-resident compare-select.
// Each WAVE owns 2 channels (S and T) and HALF the pixels (2048):
// 76 register accumulators/thread, grid = 1024 blocks = 4096 waves
// (4 blocks/CU -> 16 waves/CU for latency hiding).
// Output: two partial-sum buffers [b][k][c], combined in k_means.
__global__ __launch_bounds__(256, 4) void k_sums(const float* __restrict__ fS,
                                                 const float* __restrict__ fT,
                                                 const int* __restrict__ labels,
                                                 float* __restrict__ psS0,
                                                 float* __restrict__ psS1,
                                                 float* __restrict__ psT0,
                                                 float* __restrict__ psT1) {
    const int t = threadIdx.x;
    const int lane = t & 63;
    const int u = (blockIdx.x << 2) + (t >> 6);   // wave-unit 0..4095
    const int b = u >> 9;
    const int r = u & 511;
    const int c0 = (r >> 1) << 1;                 // channel pair c0, c0+1
    const int half = r & 1;                       // pixel half
    const size_t base = ((size_t)(b * NC) + c0) * NHW;
    const float4* pS0 = (const float4*)(fS + base);
    const float4* pS1 = (const float4*)(fS + base + NHW);
    const float4* pT0 = (const float4*)(fT + base);
    const float4* pT1 = (const float4*)(fT + base + NHW);
    const int4* lab4 = (const int4*)(labels + b * NHW);
    const int poff = half << 9;                   // float4 offset: 512 per half

    float aS0[NCLS], aS1[NCLS], aT0[NCLS], aT1[NCLS];
    #pragma unroll
    for (int k = 0; k < NCLS; ++k) { aS0[k] = aS1[k] = aT0[k] = aT1[k] = 0.f; }

    #pragma unroll 2
    for (int i = 0; i < 8; ++i) {
        const int idx = poff + lane + (i << 6);   // float4 index (4 pixels)
        const float4 vS0 = pS0[idx];
        const float4 vS1 = pS1[idx];
        const float4 vT0 = pT0[idx];
        const float4 vT1 = pT1[idx];
        const int4 l4 = lab4[idx];
        #pragma unroll
        for (int k = 0; k < NCLS; ++k) {
            const float m0 = (l4.x == k) ? 1.f : 0.f;
            const float m1 = (l4.y == k) ? 1.f : 0.f;
            const float m2 = (l4.z == k) ? 1.f : 0.f;
            const float m3 = (l4.w == k) ? 1.f : 0.f;
            aS0[k] += m0 * vS0.x + m1 * vS0.y + m2 * vS0.z + m3 * vS0.w;
            aS1[k] += m0 * vS1.x + m1 * vS1.y + m2 * vS1.z + m3 * vS1.w;
            aT0[k] += m0 * vT0.x + m1 * vT0.y + m2 * vT0.z + m3 * vT0.w;
            aT1[k] += m0 * vT1.x + m1 * vT1.y + m2 * vT1.z + m3 * vT1.w;
        }
    }
    #pragma unroll
    for (int k = 0; k < NCLS; ++k) {
        aS0[k] = wave64_sum(aS0[k]);
        aS1[k] = wave64_sum(aS1[k]);
        aT0[k] = wave64_sum(aT0[k]);
        aT1[k] = wave64_sum(aT1[k]);
    }
    if (lane == 63) {
        float* dS = half ? psS1 : psS0;
        float* dT = half ? psT1 : psT0;
        #pragma unroll
        for (int k = 0; k < NCLS; ++k) {
            *(float2*)(dS + ((size_t)(b * NCLS + k)) * NC + c0) = make_float2(aS0[k], aS1[k]);
            *(float2*)(dT + ((size_t)(b * NCLS + k)) * NC + c0) = make_float2(aT0[k], aT1[k]);
        }
    }
}

// ---------------------------------------------------------------------------
// Kernel 3: combine partial halves, means = sum/(count+eps) (into psS0/psT0),
// plus per-(b,k) center norms. One wave per (b,k); coalesced.
__global__ __launch_bounds__(64) void k_means(float* __restrict__ psS0,
                                              const float* __restrict__ psS1,
                                              float* __restrict__ psT0,
                                              const float* __restrict__ psT1,
                                              const float* __restrict__ counts,
                                              float* __restrict__ normS,
                                              float* __restrict__ normT) {
    const int bk = blockIdx.x;
    const int t = threadIdx.x;
    const float inv = 1.f / (counts[bk] + EPSM);
    const size_t row = (size_t)bk * NC;
    float aS = 0.f, aT = 0.f;
    #pragma unroll
    for (int i = 0; i < NC / 64; ++i) {
        const int c = t + i * 64;
        float mS = (psS0[row + c] + psS1[row + c]) * inv;
        float mT = (psT0[row + c] + psT1[row + c]) * inv;
        psS0[row + c] = mS; aS += mS * mS;
        psT0[row + c] = mT; aT += mT * mT;
    }
    aS = wave64_sum(aS);
    aT = wave64_sum(aT);
    if (t == 63) { normS[bk] = sqrtf(aS); normT[bk] = sqrtf(aT); }
}

// ---------------------------------------------------------------------------
// Kernel 4: per-pixel dot(f, mean[lab]) and ||f||^2, atomic-free.
// Grid: 8 b x 16 pixel-tiles x 8 c-chunks = 1024 blocks.
// Means tile in LDS as [class][65] -> gather bank = (l+ci)%32, conflict-free.
#define CCH 64
__global__ __launch_bounds__(256) void k_dots(const float* __restrict__ fS,
                                              const float* __restrict__ fT,
                                              const float* __restrict__ meansS,
                                              const float* __restrict__ meansT,
                                              const int* __restrict__ labels,
                                              float* __restrict__ part) {
    __shared__ float mS[NCLS * 65];
    __shared__ float mT[NCLS * 65];
    const int blk = blockIdx.x;
    const int chunk = blk & 7;
    const int tile  = (blk >> 3) & 15;
    const int b     = blk >> 7;
    const int t = threadIdx.x;
    const int c0 = chunk * CCH;
    const int n = tile * 256 + t;

    for (int i = t; i < NCLS * CCH; i += 256) {
        const int k = i >> 6, j = i & 63;
        mS[k * 65 + j] = meansS[((size_t)(b * NCLS + k)) * NC + c0 + j];
        mT[k * 65 + j] = meansT[((size_t)(b * NCLS + k)) * NC + c0 + j];
    }
    __syncthreads();

    const int l = labels[b * NHW + n];
    const int lc = (l >= 0 && l < NCLS) ? l : 0;
    const float* pS = fS + ((size_t)(b * NC + c0)) * NHW + n;
    const float* pT = fT + ((size_t)(b * NC + c0)) * NHW + n;
    float dS = 0.f, nS = 0.f, dT = 0.f, nT = 0.f;
    #pragma unroll 16
    for (int ci = 0; ci < CCH; ++ci) {
        const float vS = pS[(size_t)ci * NHW];
        const float vT = pT[(size_t)ci * NHW];
        const float ms = mS[lc * 65 + ci];
        const float mt = mT[lc * 65 + ci];
        dS += vS * ms; nS += vS * vS;
        dT += vT * mt; nT += vT * vT;
    }
    const int p = b * NHW + n;
    part[((size_t)(0 * 8 + chunk)) * (NB * NHW) + p] = dS;
    part[((size_t)(1 * 8 + chunk)) * (NB * NHW) + p] = nS;
    part[((size_t)(2 * 8 + chunk)) * (NB * NHW) + p] = dT;
    part[((size_t)(3 * 8 + chunk)) * (NB * NHW) + p] = nT;
}

// ---------------------------------------------------------------------------
// Kernel 5: combine partials, cosines, MSE reduce.
__global__ __launch_bounds__(256) void k_final(const float* __restrict__ part,
                                               const int* __restrict__ labels,
                                               const float* __restrict__ normS,
                                               const float* __restrict__ normT,
                                               float* __restrict__ out) {
    __shared__ float red[4];
    const int p = blockIdx.x * 256 + threadIdx.x;
    const int b = p >> 12;
    float dS = 0.f, nS = 0.f, dT = 0.f, nT = 0.f;
    #pragma unroll
    for (int ch = 0; ch < 8; ++ch) {
        dS += part[((size_t)(0 * 8 + ch)) * (NB * NHW) + p];
        nS += part[((size_t)(1 * 8 + ch)) * (NB * NHW) + p];
        dT += part[((size_t)(2 * 8 + ch)) * (NB * NHW) + p];
        nT += part[((size_t)(3 * 8 + ch)) * (NB * NHW) + p];
    }
    const int l = labels[p];
    float val = 0.f;
    if (l >= 0 && l < NCLS) {
        float cS = dS / (fmaxf(sqrtf(nS), EPSC) * fmaxf(normS[b * NCLS + l], EPSC));
        float cT = dT / (fmaxf(sqrtf(nT), EPSC) * fmaxf(normT[b * NCLS + l], EPSC));
        float d = cS - cT;
        val = d * d;
    }
    val = wave64_sum(val);
    if ((threadIdx.x & 63) == 63) red[threadIdx.x >> 6] = val;
    __syncthreads();
    if (threadIdx.x == 0)
        atomicAdd(out, (red[0] + red[1] + red[2] + red[3]) * (1.f / (NB * NHW)));
}

// ---------------------------------------------------------------------------
extern "C" void kernel_launch(void* const* d_in, const int* in_sizes, int n_in,
                              void* d_out, int out_size, void* d_ws, size_t ws_size,
                              hipStream_t stream) {
    (void)in_sizes; (void)n_in; (void)out_size; (void)ws_size;
    const float* fS     = (const float*)d_in[0];
    const float* fT     = (const float*)d_in[1];
    const int*   target = (const int*)d_in[2];

    char* ws = (char*)d_ws;
    int*   labels = (int*)  (ws + OFF_LABELS);
    float* counts = (float*)(ws + OFF_COUNTS);
    float* psS0   = (float*)(ws + OFF_SUMS_S0);   // becomes meansS
    float* psS1   = (float*)(ws + OFF_SUMS_S1);
    float* psT0   = (float*)(ws + OFF_SUMS_T0);   // becomes meansT
    float* psT1   = (float*)(ws + OFF_SUMS_T1);
    float* normS  = (float*)(ws + OFF_NORM_S);
    float* normT  = (float*)(ws + OFF_NORM_T);
    float* part   = (float*)(ws + OFF_PART);

    hipMemsetAsync(d_out, 0, sizeof(float), stream);

    k_labels<<<NB, 256, 0, stream>>>(target, labels, counts);
    k_sums  <<<NB * NC / 4, 256, 0, stream>>>(fS, fT, labels, psS0, psS1, psT0, psT1);
    k_means <<<NB * NCLS, 64, 0, stream>>>(psS0, psS1, psT0, psT1, counts, normS, normT);
    k_dots  <<<NB * 16 * 8, 256, 0, stream>>>(fS, fT, psS0, psT0, labels, part);
    k_final <<<NB * NHW / 256, 256, 0, stream>>>(part, labels, normS, normT,
                                                 (float*)d_out);
}

// Round 4
// 216.536 us; speedup vs baseline: 1.8965x; 1.8965x over previous
//
#include <hip/hip_runtime.h>

// Problem constants (B=8, C=512, H=W=64, K=19 classes)
#define NCLS   19
#define NB     8
#define NC     512
#define NHW    4096      // 64*64
#define EPSM   1e-6f     // mean denominator eps
#define EPSC   1e-8f     // cosine eps

// Workspace layout (bytes)
#define OFF_LABELS   0u          // int32 [NB*NHW]
#define OFF_COUNTS   131072u     // float [NB*NCLS]
#define OFF_SUMS_S0  132096u     // float [NB][NCLS][NC] partial half 0 (becomes means)
#define OFF_SUMS_S1  443392u     // float [NB][NCLS][NC] partial half 1
#define OFF_SUMS_T0  754688u
#define OFF_SUMS_T1  1065984u
#define OFF_NORM_S   1377280u
#define OFF_NORM_T   1378304u
#define OFF_PART     1379328u    // float [4 arrays][8 chunks][NB*NHW] = 4 MB
// total ~5.6 MB

// ---------------------------------------------------------------------------
// Wave-64 sum via DPP (VALU pipe only, no LDS). Result valid in lane 63.
template<int CTRL>
__device__ __forceinline__ float dpp_add(float x) {
    int y = __builtin_amdgcn_update_dpp(0, __float_as_int(x), CTRL, 0xf, 0xf, false);
    return x + __int_as_float(y);
}
__device__ __forceinline__ float wave64_sum(float x) {
    x = dpp_add<0x111>(x);   // row_shr:1
    x = dpp_add<0x112>(x);   // row_shr:2
    x = dpp_add<0x114>(x);   // row_shr:4
    x = dpp_add<0x118>(x);   // row_shr:8
    x = dpp_add<0x142>(x);   // row_bcast:15
    x = dpp_add<0x143>(x);   // row_bcast:31 -> lane63 has total
    return x;
}

// ---------------------------------------------------------------------------
// Kernel 1: nearest-resize labels (512x512 -> 64x64) + per-batch class counts
__global__ __launch_bounds__(256) void k_labels(const int* __restrict__ target,
                                                int* __restrict__ labels,
                                                float* __restrict__ counts) {
    __shared__ int hist[NCLS];
    const int b = blockIdx.x;
    const int t = threadIdx.x;
    if (t < NCLS) hist[t] = 0;
    __syncthreads();
    const int* tb = target + (size_t)b * 512 * 512;
    #pragma unroll
    for (int i = 0; i < 16; ++i) {
        int n = t + i * 256;
        int y = n >> 6, x = n & 63;
        int l = tb[(y * 8) * 512 + x * 8];
        labels[b * NHW + n] = l;
        if (l >= 0 && l < NCLS) atomicAdd(&hist[l], 1);
    }
    __syncthreads();
    if (t < NCLS) counts[b * NCLS + t] = (float)hist[t];
}

// ---------------------------------------------------------------------------
// Kernel 2: per-class channel sums, register-resident compare-select.
// Each WAVE owns 2 channels (S and T) and HALF the pixels (2048):
// 76 register accumulators/thread, grid = 1024 blocks = 4096 waves.
// launch_bounds min-waves MUST stay at 2: declaring 4 caps VGPR at 64 and
// spills all 76 accumulators to scratch (measured r3: WRITE_SIZE 527 MB,
// 264 us). At ~96-110 VGPR the HW still fits 4 blocks/CU (16 waves/CU).
__global__ __launch_bounds__(256, 2) void k_sums(const float* __restrict__ fS,
                                                 const float* __restrict__ fT,
                                                 const int* __restrict__ labels,
                                                 float* __restrict__ psS0,
                                                 float* __restrict__ psS1,
                                                 float* __restrict__ psT0,
                                                 float* __restrict__ psT1) {
    const int t = threadIdx.x;
    const int lane = t & 63;
    const int u = (blockIdx.x << 2) + (t >> 6);   // wave-unit 0..4095
    const int b = u >> 9;
    const int r = u & 511;
    const int c0 = (r >> 1) << 1;                 // channel pair c0, c0+1
    const int half = r & 1;                       // pixel half
    const size_t base = ((size_t)(b * NC) + c0) * NHW;
    const float4* pS0 = (const float4*)(fS + base);
    const float4* pS1 = (const float4*)(fS + base + NHW);
    const float4* pT0 = (const float4*)(fT + base);
    const float4* pT1 = (const float4*)(fT + base + NHW);
    const int4* lab4 = (const int4*)(labels + b * NHW);
    const int poff = half << 9;                   // float4 offset: 512 per half

    float aS0[NCLS], aS1[NCLS], aT0[NCLS], aT1[NCLS];
    #pragma unroll
    for (int k = 0; k < NCLS; ++k) { aS0[k] = aS1[k] = aT0[k] = aT1[k] = 0.f; }

    #pragma unroll 2
    for (int i = 0; i < 8; ++i) {
        const int idx = poff + lane + (i << 6);   // float4 index (4 pixels)
        const float4 vS0 = pS0[idx];
        const float4 vS1 = pS1[idx];
        const float4 vT0 = pT0[idx];
        const float4 vT1 = pT1[idx];
        const int4 l4 = lab4[idx];
        #pragma unroll
        for (int k = 0; k < NCLS; ++k) {
            const float m0 = (l4.x == k) ? 1.f : 0.f;
            const float m1 = (l4.y == k) ? 1.f : 0.f;
            const float m2 = (l4.z == k) ? 1.f : 0.f;
            const float m3 = (l4.w == k) ? 1.f : 0.f;
            aS0[k] += m0 * vS0.x + m1 * vS0.y + m2 * vS0.z + m3 * vS0.w;
            aS1[k] += m0 * vS1.x + m1 * vS1.y + m2 * vS1.z + m3 * vS1.w;
            aT0[k] += m0 * vT0.x + m1 * vT0.y + m2 * vT0.z + m3 * vT0.w;
            aT1[k] += m0 * vT1.x + m1 * vT1.y + m2 * vT1.z + m3 * vT1.w;
        }
    }
    #pragma unroll
    for (int k = 0; k < NCLS; ++k) {
        aS0[k] = wave64_sum(aS0[k]);
        aS1[k] = wave64_sum(aS1[k]);
        aT0[k] = wave64_sum(aT0[k]);
        aT1[k] = wave64_sum(aT1[k]);
    }
    if (lane == 63) {
        float* dS = half ? psS1 : psS0;
        float* dT = half ? psT1 : psT0;
        #pragma unroll
        for (int k = 0; k < NCLS; ++k) {
            *(float2*)(dS + ((size_t)(b * NCLS + k)) * NC + c0) = make_float2(aS0[k], aS1[k]);
            *(float2*)(dT + ((size_t)(b * NCLS + k)) * NC + c0) = make_float2(aT0[k], aT1[k]);
        }
    }
}

// ---------------------------------------------------------------------------
// Kernel 3: combine partial halves, means = sum/(count+eps) (into psS0/psT0),
// plus per-(b,k) center norms. One wave per (b,k); coalesced.
__global__ __launch_bounds__(64) void k_means(float* __restrict__ psS0,
                                              const float* __restrict__ psS1,
                                              float* __restrict__ psT0,
                                              const float* __restrict__ psT1,
                                              const float* __restrict__ counts,
                                              float* __restrict__ normS,
                                              float* __restrict__ normT) {
    const int bk = blockIdx.x;
    const int t = threadIdx.x;
    const float inv = 1.f / (counts[bk] + EPSM);
    const size_t row = (size_t)bk * NC;
    float aS = 0.f, aT = 0.f;
    #pragma unroll
    for (int i = 0; i < NC / 64; ++i) {
        const int c = t + i * 64;
        float mS = (psS0[row + c] + psS1[row + c]) * inv;
        float mT = (psT0[row + c] + psT1[row + c]) * inv;
        psS0[row + c] = mS; aS += mS * mS;
        psT0[row + c] = mT; aT += mT * mT;
    }
    aS = wave64_sum(aS);
    aT = wave64_sum(aT);
    if (t == 63) { normS[bk] = sqrtf(aS); normT[bk] = sqrtf(aT); }
}

// ---------------------------------------------------------------------------
// Kernel 4: per-pixel dot(f, mean[lab]) and ||f||^2, atomic-free.
// Grid: 8 b x 16 pixel-tiles x 8 c-chunks = 1024 blocks.
// Means tile in LDS as [class][65] -> gather bank = (l+ci)%32, conflict-free.
#define CCH 64
__global__ __launch_bounds__(256) void k_dots(const float* __restrict__ fS,
                                              const float* __restrict__ fT,
                                              const float* __restrict__ meansS,
                                              const float* __restrict__ meansT,
                                              const int* __restrict__ labels,
                                              float* __restrict__ part) {
    __shared__ float mS[NCLS * 65];
    __shared__ float mT[NCLS * 65];
    const int blk = blockIdx.x;
    const int chunk = blk & 7;
    const int tile  = (blk >> 3) & 15;
    const int b     = blk >> 7;
    const int t = threadIdx.x;
    const int c0 = chunk * CCH;
    const int n = tile * 256 + t;

    for (int i = t; i < NCLS * CCH; i += 256) {
        const int k = i >> 6, j = i & 63;
        mS[k * 65 + j] = meansS[((size_t)(b * NCLS + k)) * NC + c0 + j];
        mT[k * 65 + j] = meansT[((size_t)(b * NCLS + k)) * NC + c0 + j];
    }
    __syncthreads();

    const int l = labels[b * NHW + n];
    const int lc = (l >= 0 && l < NCLS) ? l : 0;
    const float* pS = fS + ((size_t)(b * NC + c0)) * NHW + n;
    const float* pT = fT + ((size_t)(b * NC + c0)) * NHW + n;
    float dS = 0.f, nS = 0.f, dT = 0.f, nT = 0.f;
    #pragma unroll 16
    for (int ci = 0; ci < CCH; ++ci) {
        const float vS = pS[(size_t)ci * NHW];
        const float vT = pT[(size_t)ci * NHW];
        const float ms = mS[lc * 65 + ci];
        const float mt = mT[lc * 65 + ci];
        dS += vS * ms; nS += vS * vS;
        dT += vT * mt; nT += vT * vT;
    }
    const int p = b * NHW + n;
    part[((size_t)(0 * 8 + chunk)) * (NB * NHW) + p] = dS;
    part[((size_t)(1 * 8 + chunk)) * (NB * NHW) + p] = nS;
    part[((size_t)(2 * 8 + chunk)) * (NB * NHW) + p] = dT;
    part[((size_t)(3 * 8 + chunk)) * (NB * NHW) + p] = nT;
}

// ---------------------------------------------------------------------------
// Kernel 5: combine partials, cosines, MSE reduce.
__global__ __launch_bounds__(256) void k_final(const float* __restrict__ part,
                                               const int* __restrict__ labels,
                                               const float* __restrict__ normS,
                                               const float* __restrict__ normT,
                                               float* __restrict__ out) {
    __shared__ float red[4];
    const int p = blockIdx.x * 256 + threadIdx.x;
    const int b = p >> 12;
    float dS = 0.f, nS = 0.f, dT = 0.f, nT = 0.f;
    #pragma unroll
    for (int ch = 0; ch < 8; ++ch) {
        dS += part[((size_t)(0 * 8 + ch)) * (NB * NHW) + p];
        nS += part[((size_t)(1 * 8 + ch)) * (NB * NHW) + p];
        dT += part[((size_t)(2 * 8 + ch)) * (NB * NHW) + p];
        nT += part[((size_t)(3 * 8 + ch)) * (NB * NHW) + p];
    }
    const int l = labels[p];
    float val = 0.f;
    if (l >= 0 && l < NCLS) {
        float cS = dS / (fmaxf(sqrtf(nS), EPSC) * fmaxf(normS[b * NCLS + l], EPSC));
        float cT = dT / (fmaxf(sqrtf(nT), EPSC) * fmaxf(normT[b * NCLS + l], EPSC));
        float d = cS - cT;
        val = d * d;
    }
    val = wave64_sum(val);
    if ((threadIdx.x & 63) == 63) red[threadIdx.x >> 6] = val;
    __syncthreads();
    if (threadIdx.x == 0)
        atomicAdd(out, (red[0] + red[1] + red[2] + red[3]) * (1.f / (NB * NHW)));
}

// ---------------------------------------------------------------------------
extern "C" void kernel_launch(void* const* d_in, const int* in_sizes, int n_in,
                              void* d_out, int out_size, void* d_ws, size_t ws_size,
                              hipStream_t stream) {
    (void)in_sizes; (void)n_in; (void)out_size; (void)ws_size;
    const float* fS     = (const float*)d_in[0];
    const float* fT     = (const float*)d_in[1];
    const int*   target = (const int*)d_in[2];

    char* ws = (char*)d_ws;
    int*   labels = (int*)  (ws + OFF_LABELS);
    float* counts = (float*)(ws + OFF_COUNTS);
    float* psS0   = (float*)(ws + OFF_SUMS_S0);   // becomes meansS
    float* psS1   = (float*)(ws + OFF_SUMS_S1);
    float* psT0   = (float*)(ws + OFF_SUMS_T0);   // becomes meansT
    float* psT1   = (float*)(ws + OFF_SUMS_T1);
    float* normS  = (float*)(ws + OFF_NORM_S);
    float* normT  = (float*)(ws + OFF_NORM_T);
    float* part   = (float*)(ws + OFF_PART);

    hipMemsetAsync(d_out, 0, sizeof(float), stream);

    k_labels<<<NB, 256, 0, stream>>>(target, labels, counts);
    k_sums  <<<NB * NC / 4, 256, 0, stream>>>(fS, fT, labels, psS0, psS1, psT0, psT1);
    k_means <<<NB * NCLS, 64, 0, stream>>>(psS0, psS1, psT0, psT1, counts, normS, normT);
    k_dots  <<<NB * 16 * 8, 256, 0, stream>>>(fS, fT, psS0, psT0, labels, part);
    k_final <<<NB * NHW / 256, 256, 0, stream>>>(part, labels, normS, normT,
                                                 (float*)d_out);
}